// Round 16
// baseline (68.911 us; speedup 1.0000x reference)
//
#include <hip/hip_runtime.h>
#include <hip/hip_bf16.h>
#include <math.h>

typedef short bf16x8 __attribute__((ext_vector_type(8)));
typedef float f32x4 __attribute__((ext_vector_type(4)));
typedef unsigned int u32;
typedef unsigned short u16;

constexpr int Bb = 8, LQn = 1024, LKn = 1024, En = 512, Hn = 8, Dn = 64;
constexpr int Mtok = Bb * LQn;  // 8192
// 1/sqrt(512) * log2(e): folded into K so softmax is a bare exp2
constexpr float KCOEF = 0.06376246332977306f;

__device__ __forceinline__ u16 f2bf(float f) {
  u32 u = __builtin_bit_cast(u32, f);
  u32 r = (u + 0x7fffu + ((u >> 16) & 1u)) >> 16;
  return (u16)r;
}
__device__ __forceinline__ float bf2f(u16 h) {
  u32 u = ((u32)h) << 16;
  return __builtin_bit_cast(float, u);
}
__device__ __forceinline__ u16 f2bf_hw(float f) {
  return __builtin_bit_cast(u16, __float2bfloat16(f));  // RNE
}

// async 16B global -> LDS copy (wave-uniform LDS base + lane*16 required)
__device__ __forceinline__ void async_lds16(const void* gsrc, void* ldst) {
  __builtin_amdgcn_global_load_lds(
      (const __attribute__((address_space(1))) u32*)gsrc,
      (__attribute__((address_space(3))) u32*)ldst, 16, 0, 0);
}

// ------------- unified prep: fp32->bf16 for x1/x2 (+sin-masks) and Wq/Wk/Wv -------------
// kbias is written PRE-BAKED as the score bias: 0.0 (keep) or -3e38 (masked).
__global__ void prep_kernel(const float* __restrict__ x1, const float* __restrict__ x2,
                            u16* __restrict__ x1b, u16* __restrict__ x2b,
                            float* __restrict__ qmask, float* __restrict__ kbias,
                            const float* __restrict__ Wq, const float* __restrict__ Wk,
                            const float* __restrict__ Wv, u16* __restrict__ wqb,
                            u16* __restrict__ wkb, u16* __restrict__ wvb) {
  int blk = blockIdx.x;
  if (blk < 4096) {
    int id = blk * 4 + (threadIdx.x >> 6);
    int lane = threadIdx.x & 63;
    const float* x; u16* xb; int row; bool isq;
    if (id < Mtok) { x = x1; xb = x1b; row = id; isq = true; }
    else           { x = x2; xb = x2b; row = id - Mtok; isq = false; }
    const float4* p = reinterpret_cast<const float4*>(x + (size_t)row * En);
    ushort4* ob = reinterpret_cast<ushort4*>(xb + (size_t)row * En);
    double s = 0.0;
#pragma unroll
    for (int j = 0; j < En / 256; ++j) {
      float4 v = p[lane + j * 64];
      s += (double)v.x + (double)v.y + (double)v.z + (double)v.w;
      ushort4 o;
      o.x = f2bf(v.x); o.y = f2bf(v.y); o.z = f2bf(v.z); o.w = f2bf(v.w);
      ob[lane + j * 64] = o;
    }
#pragma unroll
    for (int off = 32; off > 0; off >>= 1) s += __shfl_down(s, off, 64);
    if (lane == 0) {
      float sv = (float)sin(fabs(s));
      if (isq) qmask[row] = sv;
      else     kbias[row] = sv > 0.f ? 0.f : -3.0e38f;
    }
  } else {
    int n4 = En * En / 4;  // 65536
    int j = (blk - 4096) * 256 + threadIdx.x;
    const float* src; u16* dst;
    if (j < n4) { src = Wq; dst = wqb; }
    else if (j < 2 * n4) { src = Wk; dst = wkb; j -= n4; }
    else { src = Wv; dst = wvb; j -= 2 * n4; }
    float4 v = reinterpret_cast<const float4*>(src)[j];
    ushort4 o;
    o.x = f2bf(v.x); o.y = f2bf(v.y); o.z = f2bf(v.z); o.w = f2bf(v.w);
    reinterpret_cast<ushort4*>(dst)[j] = o;
  }
}

// ------- GEMM core: C = coef*relu(A*Bm^T + bias), 128x128 tile, 512 thr --------
// SINGLE-buffered 32KB LDS -> 3 blocks/CU; 768 blocks = one residency round.
template <int BIAS_ROW>
__device__ __forceinline__ void gemm_core(
    const u16* __restrict__ A, const u16* __restrict__ Bm,
    const float* __restrict__ bias, u16* __restrict__ C,
    int ldc, float coef, int row0, int col0) {
  constexpr int K = 512, BK = 64;
  __shared__ u16 sA[128 * BK];
  __shared__ u16 sB[128 * BK];
  int tid = threadIdx.x;
  int lane = tid & 63;
  int w = tid >> 6;
  int wm = w >> 2, wn = w & 3;
  int rgrp = lane >> 4, cidx = lane & 15;

  f32x4 acc[4][2];
#pragma unroll
  for (int mi = 0; mi < 4; ++mi)
#pragma unroll
    for (int ni = 0; ni < 2; ++ni) acc[mi][ni] = f32x4{0.f, 0.f, 0.f, 0.f};

  for (int kt = 0; kt < K / BK; ++kt) {
    int k0 = kt * BK;
    __syncthreads();  // previous compute done before overwrite
#pragma unroll
    for (int rr = 0; rr < 2; ++rr) {  // A tile: 128x64 bf16 = 1024 16B chunks
      int cid = rr * 512 + tid;
      int r = cid >> 3, c = cid & 7;
      int cg = c ^ (r & 7);
      async_lds16(A + (size_t)(row0 + r) * K + k0 + cg * 8, &sA[cid * 8]);
    }
#pragma unroll
    for (int rr = 0; rr < 2; ++rr) {  // B tile: 128x64
      int cid = rr * 512 + tid;
      int r = cid >> 3, c = cid & 7;
      int cg = c ^ (r & 7);
      async_lds16(Bm + (size_t)(col0 + r) * K + k0 + cg * 8, &sB[cid * 8]);
    }
    __syncthreads();  // drain stage (implicit vmcnt(0))
#pragma unroll
    for (int kk = 0; kk < 2; ++kk) {
      bf16x8 a[4], b[2];
#pragma unroll
      for (int mi = 0; mi < 4; ++mi) {
        int row = wm * 64 + mi * 16 + cidx;
        a[mi] = *reinterpret_cast<const bf16x8*>(
            &sA[row * BK + ((kk * 4 + rgrp) ^ (row & 7)) * 8]);
      }
#pragma unroll
      for (int ni = 0; ni < 2; ++ni) {
        int row = wn * 32 + ni * 16 + cidx;
        b[ni] = *reinterpret_cast<const bf16x8*>(
            &sB[row * BK + ((kk * 4 + rgrp) ^ (row & 7)) * 8]);
      }
#pragma unroll
      for (int mi = 0; mi < 4; ++mi)
#pragma unroll
        for (int ni = 0; ni < 2; ++ni)
          acc[mi][ni] = __builtin_amdgcn_mfma_f32_16x16x32_bf16(a[mi], b[ni], acc[mi][ni], 0, 0, 0);
    }
  }
  // epilogue: bias + relu + coef + bf16 store. C/D layout: col=lane&15, row=(lane>>4)*4+r
#pragma unroll
  for (int mi = 0; mi < 4; ++mi)
#pragma unroll
    for (int ni = 0; ni < 2; ++ni)
#pragma unroll
      for (int r = 0; r < 4; ++r) {
        int grow = row0 + wm * 64 + mi * 16 + rgrp * 4 + r;
        int gcol = col0 + wn * 32 + ni * 16 + cidx;
        float v = acc[mi][ni][r] + (BIAS_ROW ? bias[grow] : bias[gcol]);
        v = v > 0.f ? v : 0.f;
        C[(size_t)grow * ldc + gcol] = f2bf_hw(v * coef);
      }
}

// All three projections in one launch: z=0 Q, z=1 K (pre-scaled), z=2 V^T
__global__ __launch_bounds__(512, 6) void gemm3(
    const u16* __restrict__ x1b, const u16* __restrict__ wqb, const float* __restrict__ bq,
    u16* __restrict__ qbq,
    const u16* __restrict__ x2b, const u16* __restrict__ wkb, const float* __restrict__ bk,
    u16* __restrict__ kbk,
    const u16* __restrict__ wvb, const float* __restrict__ bv, u16* __restrict__ vtb) {
  int z = blockIdx.z;
  if (z == 0) {
    gemm_core<0>(x1b, wqb, bq, qbq, En, 1.0f, blockIdx.x * 128, blockIdx.y * 128);
  } else if (z == 1) {
    gemm_core<0>(x2b, wkb, bk, kbk, En, KCOEF, blockIdx.x * 128, blockIdx.y * 128);
  } else {
    // V^T = relu(Wv * x2b^T + bv): rows = feature (bias per row), cols = token
    gemm_core<1>(wvb, x2b, bv, vtb, Mtok, 1.0f, blockIdx.y * 128, blockIdx.x * 128);
  }
}

// ------- fused masked attention: QBLK=64, SINGLE-buffered K/V (24KB, 6 blk/CU) -------
// Same mechanism as the R14 GEMM win: fewer LDS bytes + more co-resident blocks
// beats double-buffer at lower occupancy. grid: (B*H, LQ/64); 4 waves x 16 q-rows.
// S^T = mfma(K, Q); kbias pre-baked C-init; packed P^T ds_write_b64; T5 on PV.
__global__ __launch_bounds__(256, 6) void attn_kernel(
    const u16* __restrict__ qb, const u16* __restrict__ kb, const u16* __restrict__ vtb,
    const float* __restrict__ kbias, const float* __restrict__ qmask,
    float* __restrict__ out) {
  __shared__ u16 sK[64 * 64];
  __shared__ u16 sV[64 * 64];       // V^T tile: rows=d (64), cols=k (64)
  __shared__ u16 sQP[64 * 64];      // Q tile, then wave-private P^T 16x64 slices
  int tid = threadIdx.x, lane = tid & 63, w = tid >> 6;
  int bh = blockIdx.x, qblk = blockIdx.y;
  int b = bh >> 3, h = bh & 7;
  int rgrp = lane >> 4, cidx = lane & 15;

  const u16* qbase = qb + ((size_t)(b * LQn) + qblk * 64) * En + h * Dn;
  const u16* kbase = kb + (size_t)(b * LKn) * En + h * Dn;
  const u16* vbase = vtb + (size_t)(h * Dn) * Mtok + b * LKn;
  const float* kmb = kbias + b * LKn;

  auto stageKV = [&](int kt) {
#pragma unroll
    for (int rr = 0; rr < 2; ++rr) {
      int cid = rr * 256 + tid;
      int r = cid >> 3, c = cid & 7;
      int cg = c ^ (r & 7);
      async_lds16(kbase + (size_t)(kt * 64 + r) * En + cg * 8, &sK[cid * 8]);
      async_lds16(vbase + (size_t)r * Mtok + kt * 64 + cg * 8, &sV[cid * 8]);
    }
  };

#pragma unroll
  for (int rr = 0; rr < 2; ++rr) {  // Q tile 64x64 into sQP
    int cid = rr * 256 + tid;
    int r = cid >> 3, c = cid & 7;
    int cg = c ^ (r & 7);
    async_lds16(qbase + (size_t)r * En + cg * 8, &sQP[cid * 8]);
  }
  stageKV(0);
  __syncthreads();  // drain Q + first K/V

  bf16x8 qa0, qa1;
  {
    int row = w * 16 + cidx;
    qa0 = *reinterpret_cast<const bf16x8*>(&sQP[row * 64 + (rgrp ^ (row & 7)) * 8]);
    qa1 = *reinterpret_cast<const bf16x8*>(&sQP[row * 64 + ((4 + rgrp) ^ (row & 7)) * 8]);
  }

  f32x4 acc_o[4];
#pragma unroll
  for (int dt = 0; dt < 4; ++dt) acc_o[dt] = f32x4{0.f, 0.f, 0.f, 0.f};
  float den = 0.f;  // per-lane: q=cidx, k in {kt*64 + ktile*16 + rgrp*4 + r}

  int prow = w * 16 + cidx;
  char* sPbyte = reinterpret_cast<char*>(sQP);

  for (int kt = 0; kt < LKn / 64; ++kt) {
    // S^T = K Q^T (per-wave 64k x 16q), P = exp2(S + kbias) -> packed P^T LDS
#pragma unroll
    for (int ktile = 0; ktile < 4; ++ktile) {
      int krow = ktile * 16 + cidx;
      bf16x8 kf0 = *reinterpret_cast<const bf16x8*>(
          &sK[krow * 64 + (rgrp ^ (krow & 7)) * 8]);
      bf16x8 kf1 = *reinterpret_cast<const bf16x8*>(
          &sK[krow * 64 + ((4 + rgrp) ^ (krow & 7)) * 8]);
      float4 km4 = *reinterpret_cast<const float4*>(&kmb[kt * 64 + ktile * 16 + rgrp * 4]);
      f32x4 s;
      s[0] = km4.x; s[1] = km4.y; s[2] = km4.z; s[3] = km4.w;  // pre-baked bias
      // swapped operands: D[k_row, q_col]; K/Q fragment bytes identical to unswapped
      s = __builtin_amdgcn_mfma_f32_16x16x32_bf16(kf0, qa0, s, 0, 0, 0);
      s = __builtin_amdgcn_mfma_f32_16x16x32_bf16(kf1, qa1, s, 0, 0, 0);
      float p0 = __builtin_amdgcn_exp2f(s[0]);
      float p1 = __builtin_amdgcn_exp2f(s[1]);
      float p2 = __builtin_amdgcn_exp2f(s[2]);
      float p3 = __builtin_amdgcn_exp2f(s[3]);
      den += (p0 + p1) + (p2 + p3);
      ushort4 pk;
      pk.x = f2bf_hw(p0); pk.y = f2bf_hw(p1); pk.z = f2bf_hw(p2); pk.w = f2bf_hw(p3);
      // P^T[q=prow][k=ktile*16+rgrp*4 .. +3]: granule=ktile*2+(rgrp>>1), half=rgrp&1
      int gran = ktile * 2 + (rgrp >> 1);
      int boff = prow * 128 + ((gran ^ (prow & 7)) << 4) + ((rgrp & 1) << 3);
      *reinterpret_cast<ushort4*>(sPbyte + boff) = pk;
    }
    // PV: out(16q x 64d) += P(16q x 64k) * V(64k x 64d); wave-private P, no barrier
    __builtin_amdgcn_s_setprio(1);  // T5: favor MFMA-entering wave
#pragma unroll
    for (int kk = 0; kk < 2; ++kk) {
      bf16x8 pa = *reinterpret_cast<const bf16x8*>(
          &sQP[prow * 64 + ((kk * 4 + rgrp) ^ (prow & 7)) * 8]);
#pragma unroll
      for (int dt = 0; dt < 4; ++dt) {
        int vrow = dt * 16 + cidx;
        bf16x8 vf = *reinterpret_cast<const bf16x8*>(
            &sV[vrow * 64 + ((kk * 4 + rgrp) ^ (vrow & 7)) * 8]);
        acc_o[dt] = __builtin_amdgcn_mfma_f32_16x16x32_bf16(pa, vf, acc_o[dt], 0, 0, 0);
      }
    }
    __builtin_amdgcn_s_setprio(0);
    if (kt < LKn / 64 - 1) {
      __syncthreads();   // all compute reads of sK/sV done
      stageKV(kt + 1);   // issue next tile
      __syncthreads();   // drain (implicit vmcnt(0)); siblings cover the stall
    }
  }
  // full denominator for q=cidx: sum across the 4 rgrp groups
  den += __shfl_xor(den, 16, 64);
  den += __shfl_xor(den, 32, 64);

  const float* qmb = qmask + (size_t)b * LQn + qblk * 64 + w * 16;
  const u16* qres = qbase + (size_t)(w * 16) * En;
  float* obase = out + ((size_t)(b * LQn) + qblk * 64 + w * 16) * En + h * Dn;
#pragma unroll
  for (int r = 0; r < 4; ++r) {
    int qr = rgrp * 4 + r;
    float denq = __shfl(den, qr, 64);  // lane qr holds full den for q=qr
    float fac = qmb[qr] / denq;
#pragma unroll
    for (int dt = 0; dt < 4; ++dt) {
      float v = acc_o[dt][r] * fac + bf2f(qres[(size_t)qr * En + dt * 16 + cidx]);
      obase[(size_t)qr * En + dt * 16 + cidx] = v;
    }
  }
}

extern "C" void kernel_launch(void* const* d_in, const int* in_sizes, int n_in,
                              void* d_out, int out_size, void* d_ws, size_t ws_size,
                              hipStream_t stream) {
  const float* x1 = (const float*)d_in[0];
  const float* x2 = (const float*)d_in[1];
  const float* Wq = (const float*)d_in[2];
  const float* bq = (const float*)d_in[3];
  const float* Wk = (const float*)d_in[4];
  const float* bk = (const float*)d_in[5];
  const float* Wv = (const float*)d_in[6];
  const float* bv = (const float*)d_in[7];
  float* out = (float*)d_out;

  char* ws = (char*)d_ws;
  size_t o = 0;
  u16* x1b = (u16*)(ws + o); o += (size_t)Mtok * En * 2;
  u16* x2b = (u16*)(ws + o); o += (size_t)Mtok * En * 2;
  u16* wqb = (u16*)(ws + o); o += (size_t)En * En * 2;
  u16* wkb = (u16*)(ws + o); o += (size_t)En * En * 2;
  u16* wvb = (u16*)(ws + o); o += (size_t)En * En * 2;
  u16* qbq = (u16*)(ws + o); o += (size_t)Mtok * En * 2;
  u16* kbk = (u16*)(ws + o); o += (size_t)Mtok * En * 2;
  u16* vtb = (u16*)(ws + o); o += (size_t)Mtok * En * 2;  // [E][Mtok] transposed
  float* kbias = (float*)(ws + o); o += (size_t)Mtok * 4;
  float* qmask = (float*)(ws + o); o += (size_t)Mtok * 4;

  // prep: 4096 mask/cvt blocks + 768 weight-cvt blocks
  prep_kernel<<<4864, 256, 0, stream>>>(x1, x2, x1b, x2b, qmask, kbias,
                                        Wq, Wk, Wv, wqb, wkb, wvb);

  dim3 g3(Mtok / 128, En / 128, 3);  // (64, 4, 3) = 768 blocks, 3/CU, 1 round
  gemm3<<<g3, 512, 0, stream>>>(x1b, wqb, bq, qbq, x2b, wkb, bk, kbk, wvb, bv, vtb);

  dim3 ga(Bb * Hn, LQn / 64);  // (64, 16)
  attn_kernel<<<ga, 256, 0, stream>>>(qbq, kbk, vtb, kbias, qmask, out);
}

// Round 17
// 64.925 us; speedup vs baseline: 1.0614x; 1.0614x over previous
//
#include <hip/hip_runtime.h>
#include <hip/hip_bf16.h>
#include <math.h>

typedef short bf16x8 __attribute__((ext_vector_type(8)));
typedef float f32x4 __attribute__((ext_vector_type(4)));
typedef unsigned int u32;
typedef unsigned short u16;

constexpr int Bb = 8, LQn = 1024, LKn = 1024, En = 512, Hn = 8, Dn = 64;
constexpr int Mtok = Bb * LQn;  // 8192
// 1/sqrt(512) * log2(e): folded into K so softmax is a bare exp2
constexpr float KCOEF = 0.06376246332977306f;

__device__ __forceinline__ u16 f2bf(float f) {
  u32 u = __builtin_bit_cast(u32, f);
  u32 r = (u + 0x7fffu + ((u >> 16) & 1u)) >> 16;
  return (u16)r;
}
__device__ __forceinline__ float bf2f(u16 h) {
  u32 u = ((u32)h) << 16;
  return __builtin_bit_cast(float, u);
}
__device__ __forceinline__ u16 f2bf_hw(float f) {
  return __builtin_bit_cast(u16, __float2bfloat16(f));  // RNE
}

// async 16B global -> LDS copy (wave-uniform LDS base + lane*16 required)
__device__ __forceinline__ void async_lds16(const void* gsrc, void* ldst) {
  __builtin_amdgcn_global_load_lds(
      (const __attribute__((address_space(1))) u32*)gsrc,
      (__attribute__((address_space(3))) u32*)ldst, 16, 0, 0);
}

// ------------- unified prep: fp32->bf16 for x1/x2 (+sin-masks) and Wq/Wk/Wv -------------
// kbias is written PRE-BAKED as the score bias: 0.0 (keep) or -3e38 (masked).
__global__ void prep_kernel(const float* __restrict__ x1, const float* __restrict__ x2,
                            u16* __restrict__ x1b, u16* __restrict__ x2b,
                            float* __restrict__ qmask, float* __restrict__ kbias,
                            const float* __restrict__ Wq, const float* __restrict__ Wk,
                            const float* __restrict__ Wv, u16* __restrict__ wqb,
                            u16* __restrict__ wkb, u16* __restrict__ wvb) {
  int blk = blockIdx.x;
  if (blk < 4096) {
    int id = blk * 4 + (threadIdx.x >> 6);
    int lane = threadIdx.x & 63;
    const float* x; u16* xb; int row; bool isq;
    if (id < Mtok) { x = x1; xb = x1b; row = id; isq = true; }
    else           { x = x2; xb = x2b; row = id - Mtok; isq = false; }
    const float4* p = reinterpret_cast<const float4*>(x + (size_t)row * En);
    ushort4* ob = reinterpret_cast<ushort4*>(xb + (size_t)row * En);
    double s = 0.0;
#pragma unroll
    for (int j = 0; j < En / 256; ++j) {
      float4 v = p[lane + j * 64];
      s += (double)v.x + (double)v.y + (double)v.z + (double)v.w;
      ushort4 o;
      o.x = f2bf(v.x); o.y = f2bf(v.y); o.z = f2bf(v.z); o.w = f2bf(v.w);
      ob[lane + j * 64] = o;
    }
#pragma unroll
    for (int off = 32; off > 0; off >>= 1) s += __shfl_down(s, off, 64);
    if (lane == 0) {
      float sv = (float)sin(fabs(s));
      if (isq) qmask[row] = sv;
      else     kbias[row] = sv > 0.f ? 0.f : -3.0e38f;
    }
  } else {
    int n4 = En * En / 4;  // 65536
    int j = (blk - 4096) * 256 + threadIdx.x;
    const float* src; u16* dst;
    if (j < n4) { src = Wq; dst = wqb; }
    else if (j < 2 * n4) { src = Wk; dst = wkb; j -= n4; }
    else { src = Wv; dst = wvb; j -= 2 * n4; }
    float4 v = reinterpret_cast<const float4*>(src)[j];
    ushort4 o;
    o.x = f2bf(v.x); o.y = f2bf(v.y); o.z = f2bf(v.z); o.w = f2bf(v.w);
    reinterpret_cast<ushort4*>(dst)[j] = o;
  }
}

// ------- GEMM core: C = coef*relu(A*Bm^T + bias), 128x128 tile, 512 thr --------
// SINGLE-buffered 32KB LDS -> 3 blocks/CU; 768 blocks = one residency round.
template <int BIAS_ROW>
__device__ __forceinline__ void gemm_core(
    const u16* __restrict__ A, const u16* __restrict__ Bm,
    const float* __restrict__ bias, u16* __restrict__ C,
    int ldc, float coef, int row0, int col0) {
  constexpr int K = 512, BK = 64;
  __shared__ u16 sA[128 * BK];
  __shared__ u16 sB[128 * BK];
  int tid = threadIdx.x;
  int lane = tid & 63;
  int w = tid >> 6;
  int wm = w >> 2, wn = w & 3;
  int rgrp = lane >> 4, cidx = lane & 15;

  f32x4 acc[4][2];
#pragma unroll
  for (int mi = 0; mi < 4; ++mi)
#pragma unroll
    for (int ni = 0; ni < 2; ++ni) acc[mi][ni] = f32x4{0.f, 0.f, 0.f, 0.f};

  for (int kt = 0; kt < K / BK; ++kt) {
    int k0 = kt * BK;
    __syncthreads();  // previous compute done before overwrite
#pragma unroll
    for (int rr = 0; rr < 2; ++rr) {  // A tile: 128x64 bf16 = 1024 16B chunks
      int cid = rr * 512 + tid;
      int r = cid >> 3, c = cid & 7;
      int cg = c ^ (r & 7);
      async_lds16(A + (size_t)(row0 + r) * K + k0 + cg * 8, &sA[cid * 8]);
    }
#pragma unroll
    for (int rr = 0; rr < 2; ++rr) {  // B tile: 128x64
      int cid = rr * 512 + tid;
      int r = cid >> 3, c = cid & 7;
      int cg = c ^ (r & 7);
      async_lds16(Bm + (size_t)(col0 + r) * K + k0 + cg * 8, &sB[cid * 8]);
    }
    __syncthreads();  // drain stage (implicit vmcnt(0))
#pragma unroll
    for (int kk = 0; kk < 2; ++kk) {
      bf16x8 a[4], b[2];
#pragma unroll
      for (int mi = 0; mi < 4; ++mi) {
        int row = wm * 64 + mi * 16 + cidx;
        a[mi] = *reinterpret_cast<const bf16x8*>(
            &sA[row * BK + ((kk * 4 + rgrp) ^ (row & 7)) * 8]);
      }
#pragma unroll
      for (int ni = 0; ni < 2; ++ni) {
        int row = wn * 32 + ni * 16 + cidx;
        b[ni] = *reinterpret_cast<const bf16x8*>(
            &sB[row * BK + ((kk * 4 + rgrp) ^ (row & 7)) * 8]);
      }
#pragma unroll
      for (int mi = 0; mi < 4; ++mi)
#pragma unroll
        for (int ni = 0; ni < 2; ++ni)
          acc[mi][ni] = __builtin_amdgcn_mfma_f32_16x16x32_bf16(a[mi], b[ni], acc[mi][ni], 0, 0, 0);
    }
  }
  // epilogue: bias + relu + coef + bf16 store. C/D layout: col=lane&15, row=(lane>>4)*4+r
#pragma unroll
  for (int mi = 0; mi < 4; ++mi)
#pragma unroll
    for (int ni = 0; ni < 2; ++ni)
#pragma unroll
      for (int r = 0; r < 4; ++r) {
        int grow = row0 + wm * 64 + mi * 16 + rgrp * 4 + r;
        int gcol = col0 + wn * 32 + ni * 16 + cidx;
        float v = acc[mi][ni][r] + (BIAS_ROW ? bias[grow] : bias[gcol]);
        v = v > 0.f ? v : 0.f;
        C[(size_t)grow * ldc + gcol] = f2bf_hw(v * coef);
      }
}

// All three projections in one launch: z=0 Q, z=1 K (pre-scaled), z=2 V^T
__global__ __launch_bounds__(512, 6) void gemm3(
    const u16* __restrict__ x1b, const u16* __restrict__ wqb, const float* __restrict__ bq,
    u16* __restrict__ qbq,
    const u16* __restrict__ x2b, const u16* __restrict__ wkb, const float* __restrict__ bk,
    u16* __restrict__ kbk,
    const u16* __restrict__ wvb, const float* __restrict__ bv, u16* __restrict__ vtb) {
  int z = blockIdx.z;
  if (z == 0) {
    gemm_core<0>(x1b, wqb, bq, qbq, En, 1.0f, blockIdx.x * 128, blockIdx.y * 128);
  } else if (z == 1) {
    gemm_core<0>(x2b, wkb, bk, kbk, En, KCOEF, blockIdx.x * 128, blockIdx.y * 128);
  } else {
    // V^T = relu(Wv * x2b^T + bv): rows = feature (bias per row), cols = token
    gemm_core<1>(wvb, x2b, bv, vtb, Mtok, 1.0f, blockIdx.y * 128, blockIdx.x * 128);
  }
}

// ---------------- fused masked attention (R14 structure + MFMA-den + cvt_pk) ----------------
// grid: (B*H, LQ/64); 4 waves x 16 q-rows; dbuf K/V; unioned Q/P LDS (40KB, 4 blk/CU).
// S^T = mfma(K, Q); kbias pre-baked C-init; packed P^T ds_write_b64; T5 on PV.
// den computed on the MATRIX pipe: acc_den = P x ones (reuses pa frags) -> lands
// as D[q=rgrp*4+r] per lane, exactly what the epilogue needs; no den shuffles.
__global__ __launch_bounds__(256, 4) void attn_kernel(
    const u16* __restrict__ qb, const u16* __restrict__ kb, const u16* __restrict__ vtb,
    const float* __restrict__ kbias, const float* __restrict__ qmask,
    float* __restrict__ out) {
  __shared__ u16 sK[2][64 * 64];
  __shared__ u16 sV[2][64 * 64];    // V^T tile: rows=d (64), cols=k (64)
  __shared__ u16 sQP[64 * 64];      // Q tile, then wave-private P^T 16x64 slices
  int tid = threadIdx.x, lane = tid & 63, w = tid >> 6;
  int bh = blockIdx.x, qblk = blockIdx.y;
  int b = bh >> 3, h = bh & 7;
  int rgrp = lane >> 4, cidx = lane & 15;

  const u16* qbase = qb + ((size_t)(b * LQn) + qblk * 64) * En + h * Dn;
  const u16* kbase = kb + (size_t)(b * LKn) * En + h * Dn;
  const u16* vbase = vtb + (size_t)(h * Dn) * Mtok + b * LKn;
  const float* kmb = kbias + b * LKn;

  auto stageKV = [&](int kt, int buf) {
#pragma unroll
    for (int rr = 0; rr < 2; ++rr) {
      int cid = rr * 256 + tid;
      int r = cid >> 3, c = cid & 7;
      int cg = c ^ (r & 7);
      async_lds16(kbase + (size_t)(kt * 64 + r) * En + cg * 8, &sK[buf][cid * 8]);
      async_lds16(vbase + (size_t)r * Mtok + kt * 64 + cg * 8, &sV[buf][cid * 8]);
    }
  };

#pragma unroll
  for (int rr = 0; rr < 2; ++rr) {  // Q tile 64x64 into sQP
    int cid = rr * 256 + tid;
    int r = cid >> 3, c = cid & 7;
    int cg = c ^ (r & 7);
    async_lds16(qbase + (size_t)r * En + cg * 8, &sQP[cid * 8]);
  }
  stageKV(0, 0);
  __syncthreads();

  bf16x8 qa0, qa1;
  {
    int row = w * 16 + cidx;
    qa0 = *reinterpret_cast<const bf16x8*>(&sQP[row * 64 + (rgrp ^ (row & 7)) * 8]);
    qa1 = *reinterpret_cast<const bf16x8*>(&sQP[row * 64 + ((4 + rgrp) ^ (row & 7)) * 8]);
  }
  // all-ones bf16 B-fragment for the den MFMA
  bf16x8 ones;
#pragma unroll
  for (int e = 0; e < 8; ++e) ones[e] = (short)0x3F80;

  f32x4 acc_o[4];
#pragma unroll
  for (int dt = 0; dt < 4; ++dt) acc_o[dt] = f32x4{0.f, 0.f, 0.f, 0.f};
  f32x4 acc_den = f32x4{0.f, 0.f, 0.f, 0.f};  // den[q=rgrp*4+r], all cols equal

  int prow = w * 16 + cidx;
  char* sPbyte = reinterpret_cast<char*>(sQP);

  for (int kt = 0; kt < LKn / 64; ++kt) {
    int cur = kt & 1;
    if (kt < LKn / 64 - 1) stageKV(kt + 1, cur ^ 1);  // prefetch before compute
    // S^T = K Q^T (per-wave 64k x 16q), P = exp2(S + kbias) -> packed P^T LDS
#pragma unroll
    for (int ktile = 0; ktile < 4; ++ktile) {
      int krow = ktile * 16 + cidx;
      bf16x8 kf0 = *reinterpret_cast<const bf16x8*>(
          &sK[cur][krow * 64 + (rgrp ^ (krow & 7)) * 8]);
      bf16x8 kf1 = *reinterpret_cast<const bf16x8*>(
          &sK[cur][krow * 64 + ((4 + rgrp) ^ (krow & 7)) * 8]);
      float4 km4 = *reinterpret_cast<const float4*>(&kmb[kt * 64 + ktile * 16 + rgrp * 4]);
      f32x4 s;
      s[0] = km4.x; s[1] = km4.y; s[2] = km4.z; s[3] = km4.w;  // pre-baked bias
      // swapped operands: D[k_row, q_col]; K/Q fragment bytes identical to unswapped
      s = __builtin_amdgcn_mfma_f32_16x16x32_bf16(kf0, qa0, s, 0, 0, 0);
      s = __builtin_amdgcn_mfma_f32_16x16x32_bf16(kf1, qa1, s, 0, 0, 0);
      float p0 = __builtin_amdgcn_exp2f(s[0]);
      float p1 = __builtin_amdgcn_exp2f(s[1]);
      float p2 = __builtin_amdgcn_exp2f(s[2]);
      float p3 = __builtin_amdgcn_exp2f(s[3]);
      u32 w0, w1;
      asm("v_cvt_pk_bf16_f32 %0, %1, %2" : "=v"(w0) : "v"(p0), "v"(p1));
      asm("v_cvt_pk_bf16_f32 %0, %1, %2" : "=v"(w1) : "v"(p2), "v"(p3));
      // P^T[q=prow][k=ktile*16+rgrp*4 .. +3]: granule=ktile*2+(rgrp>>1), half=rgrp&1
      int gran = ktile * 2 + (rgrp >> 1);
      int boff = prow * 128 + ((gran ^ (prow & 7)) << 4) + ((rgrp & 1) << 3);
      uint2 pk2; pk2.x = w0; pk2.y = w1;
      *reinterpret_cast<uint2*>(sPbyte + boff) = pk2;
    }
    // PV: out(16q x 64d) += P(16q x 64k) * V(64k x 64d); wave-private P, no barrier
    __builtin_amdgcn_s_setprio(1);  // T5: favor MFMA-entering wave
#pragma unroll
    for (int kk = 0; kk < 2; ++kk) {
      bf16x8 pa = *reinterpret_cast<const bf16x8*>(
          &sQP[prow * 64 + ((kk * 4 + rgrp) ^ (prow & 7)) * 8]);
      acc_den = __builtin_amdgcn_mfma_f32_16x16x32_bf16(pa, ones, acc_den, 0, 0, 0);
#pragma unroll
      for (int dt = 0; dt < 4; ++dt) {
        int vrow = dt * 16 + cidx;
        bf16x8 vf = *reinterpret_cast<const bf16x8*>(
            &sV[cur][vrow * 64 + ((kk * 4 + rgrp) ^ (vrow & 7)) * 8]);
        acc_o[dt] = __builtin_amdgcn_mfma_f32_16x16x32_bf16(pa, vf, acc_o[dt], 0, 0, 0);
      }
    }
    __builtin_amdgcn_s_setprio(0);
    __syncthreads();  // drain (covers next-tile prefetch) after full compute phase
  }

  const float* qmb = qmask + (size_t)b * LQn + qblk * 64 + w * 16;
  const u16* qres = qbase + (size_t)(w * 16) * En;
  float* obase = out + ((size_t)(b * LQn) + qblk * 64 + w * 16) * En + h * Dn;
#pragma unroll
  for (int r = 0; r < 4; ++r) {
    int qr = rgrp * 4 + r;
    float fac = qmb[qr] / acc_den[r];  // den[q] landed in-lane via the ones-MFMA
#pragma unroll
    for (int dt = 0; dt < 4; ++dt) {
      float v = acc_o[dt][r] * fac + bf2f(qres[(size_t)qr * En + dt * 16 + cidx]);
      obase[(size_t)qr * En + dt * 16 + cidx] = v;
    }
  }
}

extern "C" void kernel_launch(void* const* d_in, const int* in_sizes, int n_in,
                              void* d_out, int out_size, void* d_ws, size_t ws_size,
                              hipStream_t stream) {
  const float* x1 = (const float*)d_in[0];
  const float* x2 = (const float*)d_in[1];
  const float* Wq = (const float*)d_in[2];
  const float* bq = (const float*)d_in[3];
  const float* Wk = (const float*)d_in[4];
  const float* bk = (const float*)d_in[5];
  const float* Wv = (const float*)d_in[6];
  const float* bv = (const float*)d_in[7];
  float* out = (float*)d_out;

  char* ws = (char*)d_ws;
  size_t o = 0;
  u16* x1b = (u16*)(ws + o); o += (size_t)Mtok * En * 2;
  u16* x2b = (u16*)(ws + o); o += (size_t)Mtok * En * 2;
  u16* wqb = (u16*)(ws + o); o += (size_t)En * En * 2;
  u16* wkb = (u16*)(ws + o); o += (size_t)En * En * 2;
  u16* wvb = (u16*)(ws + o); o += (size_t)En * En * 2;
  u16* qbq = (u16*)(ws + o); o += (size_t)Mtok * En * 2;
  u16* kbk = (u16*)(ws + o); o += (size_t)Mtok * En * 2;
  u16* vtb = (u16*)(ws + o); o += (size_t)Mtok * En * 2;  // [E][Mtok] transposed
  float* kbias = (float*)(ws + o); o += (size_t)Mtok * 4;
  float* qmask = (float*)(ws + o); o += (size_t)Mtok * 4;

  // prep: 4096 mask/cvt blocks + 768 weight-cvt blocks
  prep_kernel<<<4864, 256, 0, stream>>>(x1, x2, x1b, x2b, qmask, kbias,
                                        Wq, Wk, Wv, wqb, wkb, wvb);

  dim3 g3(Mtok / 128, En / 128, 3);  // (64, 4, 3) = 768 blocks, 3/CU, 1 round
  gemm3<<<g3, 512, 0, stream>>>(x1b, wqb, bq, qbq, x2b, wkb, bk, kbk, wvb, bv, vtb);

  dim3 ga(Bb * Hn, LQn / 64);  // (64, 16)
  attn_kernel<<<ga, 256, 0, stream>>>(qbq, kbk, vtb, kbias, qmask, out);
}

// Round 18
// 64.131 us; speedup vs baseline: 1.0745x; 1.0124x over previous
//
#include <hip/hip_runtime.h>
#include <hip/hip_bf16.h>
#include <math.h>

typedef short bf16x8 __attribute__((ext_vector_type(8)));
typedef float f32x4 __attribute__((ext_vector_type(4)));
typedef unsigned int u32;
typedef unsigned short u16;

constexpr int Bb = 8, LQn = 1024, LKn = 1024, En = 512, Hn = 8, Dn = 64;
constexpr int Mtok = Bb * LQn;  // 8192
// 1/sqrt(512) * log2(e): folded into K so softmax is a bare exp2
constexpr float KCOEF = 0.06376246332977306f;

__device__ __forceinline__ u16 f2bf(float f) {
  u32 u = __builtin_bit_cast(u32, f);
  u32 r = (u + 0x7fffu + ((u >> 16) & 1u)) >> 16;
  return (u16)r;
}
__device__ __forceinline__ float bf2f(u16 h) {
  u32 u = ((u32)h) << 16;
  return __builtin_bit_cast(float, u);
}
__device__ __forceinline__ u16 f2bf_hw(float f) {
  return __builtin_bit_cast(u16, __float2bfloat16(f));  // RNE
}

// async 16B global -> LDS copy (wave-uniform LDS base + lane*16 required)
__device__ __forceinline__ void async_lds16(const void* gsrc, void* ldst) {
  __builtin_amdgcn_global_load_lds(
      (const __attribute__((address_space(1))) u32*)gsrc,
      (__attribute__((address_space(3))) u32*)ldst, 16, 0, 0);
}

// ------------- unified prep: fp32->bf16 for x1/x2 (+sin-masks) and Wq/Wk/Wv -------------
// kbias is written PRE-BAKED as the score bias: 0.0 (keep) or -3e38 (masked).
__global__ void prep_kernel(const float* __restrict__ x1, const float* __restrict__ x2,
                            u16* __restrict__ x1b, u16* __restrict__ x2b,
                            float* __restrict__ qmask, float* __restrict__ kbias,
                            const float* __restrict__ Wq, const float* __restrict__ Wk,
                            const float* __restrict__ Wv, u16* __restrict__ wqb,
                            u16* __restrict__ wkb, u16* __restrict__ wvb) {
  int blk = blockIdx.x;
  if (blk < 4096) {
    int id = blk * 4 + (threadIdx.x >> 6);
    int lane = threadIdx.x & 63;
    const float* x; u16* xb; int row; bool isq;
    if (id < Mtok) { x = x1; xb = x1b; row = id; isq = true; }
    else           { x = x2; xb = x2b; row = id - Mtok; isq = false; }
    const float4* p = reinterpret_cast<const float4*>(x + (size_t)row * En);
    ushort4* ob = reinterpret_cast<ushort4*>(xb + (size_t)row * En);
    double s = 0.0;
#pragma unroll
    for (int j = 0; j < En / 256; ++j) {
      float4 v = p[lane + j * 64];
      s += (double)v.x + (double)v.y + (double)v.z + (double)v.w;
      ushort4 o;
      o.x = f2bf(v.x); o.y = f2bf(v.y); o.z = f2bf(v.z); o.w = f2bf(v.w);
      ob[lane + j * 64] = o;
    }
#pragma unroll
    for (int off = 32; off > 0; off >>= 1) s += __shfl_down(s, off, 64);
    if (lane == 0) {
      float sv = (float)sin(fabs(s));
      if (isq) qmask[row] = sv;
      else     kbias[row] = sv > 0.f ? 0.f : -3.0e38f;
    }
  } else {
    int n4 = En * En / 4;  // 65536
    int j = (blk - 4096) * 256 + threadIdx.x;
    const float* src; u16* dst;
    if (j < n4) { src = Wq; dst = wqb; }
    else if (j < 2 * n4) { src = Wk; dst = wkb; j -= n4; }
    else { src = Wv; dst = wvb; j -= 2 * n4; }
    float4 v = reinterpret_cast<const float4*>(src)[j];
    ushort4 o;
    o.x = f2bf(v.x); o.y = f2bf(v.y); o.z = f2bf(v.z); o.w = f2bf(v.w);
    reinterpret_cast<ushort4*>(dst)[j] = o;
  }
}

// ------- GEMM core: C = coef*relu(A*Bm^T + bias), 128x128 tile, 512 thr --------
// SINGLE-buffered 32KB LDS -> 3 blocks/CU; 768 blocks = one residency round.
template <int BIAS_ROW>
__device__ __forceinline__ void gemm_core(
    const u16* __restrict__ A, const u16* __restrict__ Bm,
    const float* __restrict__ bias, u16* __restrict__ C,
    int ldc, float coef, int row0, int col0) {
  constexpr int K = 512, BK = 64;
  __shared__ u16 sA[128 * BK];
  __shared__ u16 sB[128 * BK];
  int tid = threadIdx.x;
  int lane = tid & 63;
  int w = tid >> 6;
  int wm = w >> 2, wn = w & 3;
  int rgrp = lane >> 4, cidx = lane & 15;

  f32x4 acc[4][2];
#pragma unroll
  for (int mi = 0; mi < 4; ++mi)
#pragma unroll
    for (int ni = 0; ni < 2; ++ni) acc[mi][ni] = f32x4{0.f, 0.f, 0.f, 0.f};

  for (int kt = 0; kt < K / BK; ++kt) {
    int k0 = kt * BK;
    __syncthreads();  // previous compute done before overwrite
#pragma unroll
    for (int rr = 0; rr < 2; ++rr) {  // A tile: 128x64 bf16 = 1024 16B chunks
      int cid = rr * 512 + tid;
      int r = cid >> 3, c = cid & 7;
      int cg = c ^ (r & 7);
      async_lds16(A + (size_t)(row0 + r) * K + k0 + cg * 8, &sA[cid * 8]);
    }
#pragma unroll
    for (int rr = 0; rr < 2; ++rr) {  // B tile: 128x64
      int cid = rr * 512 + tid;
      int r = cid >> 3, c = cid & 7;
      int cg = c ^ (r & 7);
      async_lds16(Bm + (size_t)(col0 + r) * K + k0 + cg * 8, &sB[cid * 8]);
    }
    __syncthreads();  // drain stage (implicit vmcnt(0))
#pragma unroll
    for (int kk = 0; kk < 2; ++kk) {
      bf16x8 a[4], b[2];
#pragma unroll
      for (int mi = 0; mi < 4; ++mi) {
        int row = wm * 64 + mi * 16 + cidx;
        a[mi] = *reinterpret_cast<const bf16x8*>(
            &sA[row * BK + ((kk * 4 + rgrp) ^ (row & 7)) * 8]);
      }
#pragma unroll
      for (int ni = 0; ni < 2; ++ni) {
        int row = wn * 32 + ni * 16 + cidx;
        b[ni] = *reinterpret_cast<const bf16x8*>(
            &sB[row * BK + ((kk * 4 + rgrp) ^ (row & 7)) * 8]);
      }
#pragma unroll
      for (int mi = 0; mi < 4; ++mi)
#pragma unroll
        for (int ni = 0; ni < 2; ++ni)
          acc[mi][ni] = __builtin_amdgcn_mfma_f32_16x16x32_bf16(a[mi], b[ni], acc[mi][ni], 0, 0, 0);
    }
  }
  // epilogue: bias + relu + coef + bf16 store. C/D layout: col=lane&15, row=(lane>>4)*4+r
#pragma unroll
  for (int mi = 0; mi < 4; ++mi)
#pragma unroll
    for (int ni = 0; ni < 2; ++ni)
#pragma unroll
      for (int r = 0; r < 4; ++r) {
        int grow = row0 + wm * 64 + mi * 16 + rgrp * 4 + r;
        int gcol = col0 + wn * 32 + ni * 16 + cidx;
        float v = acc[mi][ni][r] + (BIAS_ROW ? bias[grow] : bias[gcol]);
        v = v > 0.f ? v : 0.f;
        C[(size_t)grow * ldc + gcol] = f2bf_hw(v * coef);
      }
}

// All three projections in one launch: z=0 Q, z=1 K (pre-scaled), z=2 V^T
__global__ __launch_bounds__(512, 6) void gemm3(
    const u16* __restrict__ x1b, const u16* __restrict__ wqb, const float* __restrict__ bq,
    u16* __restrict__ qbq,
    const u16* __restrict__ x2b, const u16* __restrict__ wkb, const float* __restrict__ bk,
    u16* __restrict__ kbk,
    const u16* __restrict__ wvb, const float* __restrict__ bv, u16* __restrict__ vtb) {
  int z = blockIdx.z;
  if (z == 0) {
    gemm_core<0>(x1b, wqb, bq, qbq, En, 1.0f, blockIdx.x * 128, blockIdx.y * 128);
  } else if (z == 1) {
    gemm_core<0>(x2b, wkb, bk, kbk, En, KCOEF, blockIdx.x * 128, blockIdx.y * 128);
  } else {
    // V^T = relu(Wv * x2b^T + bv): rows = feature (bias per row), cols = token
    gemm_core<1>(wvb, x2b, bv, vtb, Mtok, 1.0f, blockIdx.y * 128, blockIdx.x * 128);
  }
}

// ------------ fused masked attention (R14 structure + hoisted LDS addressing) ------------
// grid: (B*H, LQ/64); 4 waves x 16 q-rows; dbuf K/V; unioned Q/P LDS (40KB, 4 blk/CU).
// All LDS fragment byte-offsets are precomputed ONCE (loop-invariant per lane);
// the kt-loop is unrolled x2 so the dbuf offset (half*16384B) is a compile-time
// immediate folded into ds_read offset: -> near-zero per-iteration address VALU.
// den on the matrix pipe (P x ones); packed P^T via cvt_pk; T5 on PV.
__global__ __launch_bounds__(256, 4) void attn_kernel(
    const u16* __restrict__ qb, const u16* __restrict__ kb, const u16* __restrict__ vtb,
    const float* __restrict__ kbias, const float* __restrict__ qmask,
    float* __restrict__ out) {
  __shared__ u16 sK[2][64 * 64];
  __shared__ u16 sV[2][64 * 64];    // V^T tile: rows=d (64), cols=k (64)
  __shared__ u16 sQP[64 * 64];      // Q tile, then wave-private P^T 16x64 slices
  int tid = threadIdx.x, lane = tid & 63, w = tid >> 6;
  int bh = blockIdx.x, qblk = blockIdx.y;
  int b = bh >> 3, h = bh & 7;
  int rgrp = lane >> 4, cidx = lane & 15;

  const u16* qbase = qb + ((size_t)(b * LQn) + qblk * 64) * En + h * Dn;
  const u16* kbase = kb + (size_t)(b * LKn) * En + h * Dn;
  const u16* vbase = vtb + (size_t)(h * Dn) * Mtok + b * LKn;
  const float* kmb = kbias + b * LKn;

  // stage source/dest offsets (per-lane, loop-invariant except kt)
  int scid0 = tid, scid1 = 256 + tid;
  int sr0 = scid0 >> 3, sc0 = (scid0 & 7) ^ (sr0 & 7);
  int sr1 = scid1 >> 3, sc1 = (scid1 & 7) ^ (sr1 & 7);
  auto stageKV = [&](int kt, int buf) {
    async_lds16(kbase + (size_t)(kt * 64 + sr0) * En + sc0 * 8, &sK[buf][scid0 * 8]);
    async_lds16(vbase + (size_t)sr0 * Mtok + kt * 64 + sc0 * 8, &sV[buf][scid0 * 8]);
    async_lds16(kbase + (size_t)(kt * 64 + sr1) * En + sc1 * 8, &sK[buf][scid1 * 8]);
    async_lds16(vbase + (size_t)sr1 * Mtok + kt * 64 + sc1 * 8, &sV[buf][scid1 * 8]);
  };

#pragma unroll
  for (int rr = 0; rr < 2; ++rr) {  // Q tile 64x64 into sQP
    int cid = rr * 256 + tid;
    int r = cid >> 3, c = cid & 7;
    int cg = c ^ (r & 7);
    async_lds16(qbase + (size_t)r * En + cg * 8, &sQP[cid * 8]);
  }
  stageKV(0, 0);
  __syncthreads();

  bf16x8 qa0, qa1;
  {
    int row = w * 16 + cidx;
    qa0 = *reinterpret_cast<const bf16x8*>(&sQP[row * 64 + (rgrp ^ (row & 7)) * 8]);
    qa1 = *reinterpret_cast<const bf16x8*>(&sQP[row * 64 + ((4 + rgrp) ^ (row & 7)) * 8]);
  }
  // all-ones bf16 B-fragment for the den MFMA
  bf16x8 ones;
#pragma unroll
  for (int e = 0; e < 8; ++e) ones[e] = (short)0x3F80;

  // ---- precomputed LDS byte-offsets (loop-invariant per lane) ----
  char* sKb = reinterpret_cast<char*>(sK);
  char* sVb = reinterpret_cast<char*>(sV);
  char* sPbyte = reinterpret_cast<char*>(sQP);
  int prow = w * 16 + cidx;
  u32 koffb[4][2];   // K frag reads, buf 0
#pragma unroll
  for (int ktile = 0; ktile < 4; ++ktile) {
    int krow = ktile * 16 + cidx;
    koffb[ktile][0] = (u32)(krow * 128 + ((rgrp ^ (krow & 7)) * 16));
    koffb[ktile][1] = (u32)(krow * 128 + (((4 + rgrp) ^ (krow & 7)) * 16));
  }
  u32 voffb[2][4];   // V frag reads [kk][dt], buf 0
#pragma unroll
  for (int kk = 0; kk < 2; ++kk)
#pragma unroll
    for (int dt = 0; dt < 4; ++dt) {
      int vrow = dt * 16 + cidx;
      voffb[kk][dt] = (u32)(vrow * 128 + (((kk * 4 + rgrp) ^ (vrow & 7)) * 16));
    }
  u32 pwoff[4];      // P^T packed writes per ktile
#pragma unroll
  for (int ktile = 0; ktile < 4; ++ktile) {
    int gran = ktile * 2 + (rgrp >> 1);
    pwoff[ktile] = (u32)(prow * 128 + ((gran ^ (prow & 7)) << 4) + ((rgrp & 1) << 3));
  }
  u32 paoff[2];      // PV A-frag reads per kk
#pragma unroll
  for (int kk = 0; kk < 2; ++kk)
    paoff[kk] = (u32)(prow * 128 + (((kk * 4 + rgrp) ^ (prow & 7)) * 16));

  f32x4 acc_o[4];
#pragma unroll
  for (int dt = 0; dt < 4; ++dt) acc_o[dt] = f32x4{0.f, 0.f, 0.f, 0.f};
  f32x4 acc_den = f32x4{0.f, 0.f, 0.f, 0.f};  // den[q=rgrp*4+r]

  const float* kmrow = kmb + rgrp * 4;  // per-lane mask base, bumped by 64/iter

  for (int kt2 = 0; kt2 < 8; ++kt2) {
#pragma unroll
    for (int half = 0; half < 2; ++half) {   // half == cur (compile-time)
      int kt = kt2 * 2 + half;
      if (kt < 15) stageKV(kt + 1, half ^ 1);  // prefetch before compute
      // S^T = K Q^T, P = exp2(S + kbias) -> packed P^T LDS
#pragma unroll
      for (int ktile = 0; ktile < 4; ++ktile) {
        bf16x8 kf0 = *reinterpret_cast<const bf16x8*>(sKb + half * 8192 + koffb[ktile][0]);
        bf16x8 kf1 = *reinterpret_cast<const bf16x8*>(sKb + half * 8192 + koffb[ktile][1]);
        float4 km4 = *reinterpret_cast<const float4*>(kmrow + ktile * 16);
        f32x4 s;
        s[0] = km4.x; s[1] = km4.y; s[2] = km4.z; s[3] = km4.w;  // pre-baked bias
        s = __builtin_amdgcn_mfma_f32_16x16x32_bf16(kf0, qa0, s, 0, 0, 0);
        s = __builtin_amdgcn_mfma_f32_16x16x32_bf16(kf1, qa1, s, 0, 0, 0);
        float p0 = __builtin_amdgcn_exp2f(s[0]);
        float p1 = __builtin_amdgcn_exp2f(s[1]);
        float p2 = __builtin_amdgcn_exp2f(s[2]);
        float p3 = __builtin_amdgcn_exp2f(s[3]);
        u32 w0, w1;
        asm("v_cvt_pk_bf16_f32 %0, %1, %2" : "=v"(w0) : "v"(p0), "v"(p1));
        asm("v_cvt_pk_bf16_f32 %0, %1, %2" : "=v"(w1) : "v"(p2), "v"(p3));
        uint2 pk2; pk2.x = w0; pk2.y = w1;
        *reinterpret_cast<uint2*>(sPbyte + pwoff[ktile]) = pk2;
      }
      // PV + den: wave-private P, no barrier needed before reads
      __builtin_amdgcn_s_setprio(1);  // T5
#pragma unroll
      for (int kk = 0; kk < 2; ++kk) {
        bf16x8 pa = *reinterpret_cast<const bf16x8*>(sPbyte + paoff[kk]);
        acc_den = __builtin_amdgcn_mfma_f32_16x16x32_bf16(pa, ones, acc_den, 0, 0, 0);
#pragma unroll
        for (int dt = 0; dt < 4; ++dt) {
          bf16x8 vf = *reinterpret_cast<const bf16x8*>(sVb + half * 8192 + voffb[kk][dt]);
          acc_o[dt] = __builtin_amdgcn_mfma_f32_16x16x32_bf16(pa, vf, acc_o[dt], 0, 0, 0);
        }
      }
      __builtin_amdgcn_s_setprio(0);
      kmrow += 64;
      __syncthreads();  // drain (covers next-tile prefetch) after full compute phase
    }
  }

  const float* qmb = qmask + (size_t)b * LQn + qblk * 64 + w * 16;
  const u16* qres = qbase + (size_t)(w * 16) * En;
  float* obase = out + ((size_t)(b * LQn) + qblk * 64 + w * 16) * En + h * Dn;
#pragma unroll
  for (int r = 0; r < 4; ++r) {
    int qr = rgrp * 4 + r;
    float fac = qmb[qr] / acc_den[r];  // den[q] landed in-lane via the ones-MFMA
#pragma unroll
    for (int dt = 0; dt < 4; ++dt) {
      float v = acc_o[dt][r] * fac + bf2f(qres[(size_t)qr * En + dt * 16 + cidx]);
      obase[(size_t)qr * En + dt * 16 + cidx] = v;
    }
  }
}

extern "C" void kernel_launch(void* const* d_in, const int* in_sizes, int n_in,
                              void* d_out, int out_size, void* d_ws, size_t ws_size,
                              hipStream_t stream) {
  const float* x1 = (const float*)d_in[0];
  const float* x2 = (const float*)d_in[1];
  const float* Wq = (const float*)d_in[2];
  const float* bq = (const float*)d_in[3];
  const float* Wk = (const float*)d_in[4];
  const float* bk = (const float*)d_in[5];
  const float* Wv = (const float*)d_in[6];
  const float* bv = (const float*)d_in[7];
  float* out = (float*)d_out;

  char* ws = (char*)d_ws;
  size_t o = 0;
  u16* x1b = (u16*)(ws + o); o += (size_t)Mtok * En * 2;
  u16* x2b = (u16*)(ws + o); o += (size_t)Mtok * En * 2;
  u16* wqb = (u16*)(ws + o); o += (size_t)En * En * 2;
  u16* wkb = (u16*)(ws + o); o += (size_t)En * En * 2;
  u16* wvb = (u16*)(ws + o); o += (size_t)En * En * 2;
  u16* qbq = (u16*)(ws + o); o += (size_t)Mtok * En * 2;
  u16* kbk = (u16*)(ws + o); o += (size_t)Mtok * En * 2;
  u16* vtb = (u16*)(ws + o); o += (size_t)Mtok * En * 2;  // [E][Mtok] transposed
  float* kbias = (float*)(ws + o); o += (size_t)Mtok * 4;
  float* qmask = (float*)(ws + o); o += (size_t)Mtok * 4;

  // prep: 4096 mask/cvt blocks + 768 weight-cvt blocks
  prep_kernel<<<4864, 256, 0, stream>>>(x1, x2, x1b, x2b, qmask, kbias,
                                        Wq, Wk, Wv, wqb, wkb, wvb);

  dim3 g3(Mtok / 128, En / 128, 3);  // (64, 4, 3) = 768 blocks, 3/CU, 1 round
  gemm3<<<g3, 512, 0, stream>>>(x1b, wqb, bq, qbq, x2b, wkb, bk, kbk, wvb, bv, vtb);

  dim3 ga(Bb * Hn, LQn / 64);  // (64, 16)
  attn_kernel<<<ga, 256, 0, stream>>>(qbq, kbk, vtb, kbias, qmask, out);
}